// Round 8
// baseline (142.336 us; speedup 1.0000x reference)
//
#include <hip/hip_runtime.h>
#include <hip/hip_bf16.h>
#include <math.h>

#define K_B 32
#define NRELD 16
#define PSZ 128
#define HID 768

using bf16x8 = __attribute__((ext_vector_type(8))) short;
using f32x4  = __attribute__((ext_vector_type(4))) float;

__device__ __forceinline__ unsigned int f2bf(float x) {   // fp32 -> bf16 bits (RNE)
    unsigned int u = __float_as_uint(x);
    return (u + 0x7fffu + ((u >> 16) & 1u)) >> 16;
}

// =========================================================================
// K_A (k_Y): self-sufficient. Per block (r = bid&15, gs = bid>>4, g-slab 32):
//   phase -1: ranks + gated S histograms (hist aliases AS region)
//   main:     Y_r[p, g-slab] = P0 x Rel_r  (AS staged from P0 f32 on the fly)
//   phase 2:  prop[k, g-slab] += S_r x Ytile   (atomicAdd onto 0xAA poison,
//             poison-as-float ~ -1.4e-13 — negligible, no pre-zero needed)
// grid 384, 256 thr
// =========================================================================
__global__ __launch_bounds__(256) void k_Y(
        const int* __restrict__ labels, const int* __restrict__ relIds,
        const float* __restrict__ rel, const float* __restrict__ P0,
        unsigned short* __restrict__ Y_bf, float* __restrict__ prop)
{
    __shared__ __align__(16) char blob[49152];    // AS 32K | BS 8K | SS 8K
    unsigned short* AS  = (unsigned short*)blob;              // [p][h-chunk], c^=(p&7)
    unsigned short* BS  = (unsigned short*)(blob + 32768);    // [g][h-chunk], c^=((g>>2)&7)
    unsigned short* SS  = (unsigned short*)(blob + 40960);    // [k][p], c^=(k&7)
    unsigned short* YST = (unsigned short*)blob;              // phase2 alias of AS
    int* hist = (int*)blob;                                   // phase-1 alias: [k][p] 16K
    __shared__ int lab[32], rankS[32], rowAcc[32];

    const int bid = blockIdx.x, t = threadIdx.x;
    const int wave = t >> 6, lane = t & 63;
    const int r = bid & 15, gs = bid >> 4;
    const int g0 = gs * 32;

    // issue first rel loads early (latency hidden under histogram phase)
    const int gq2 = t & 7;
    const int hq  = t >> 3;
    const size_t relb = (size_t)r*HID*HID + g0;
    float4 buf[4];
    #pragma unroll
    for (int rr = 0; rr < 4; ++rr)
        buf[rr] = *(const float4*)&rel[relb + (size_t)(hq*4 + rr)*HID + gq2*4];

    if (t < 32) { lab[t] = labels[t]; rowAcc[t] = 0; }
    for (int i = t; i < 4096; i += 256) hist[i] = 0;
    __syncthreads();
    if (t < 32) { int rk = 0; for (int j = 0; j < 32; ++j) rk += (lab[j] < lab[t]); rankS[t] = rk; }
    __syncthreads();
    {   // histogram: thread (k = t>>3, 16 ids starting at (t&7)*16)
        int k = t >> 3, j0 = (t & 7) * 16;
        const int* rp = relIds + ((size_t)rankS[k]*NRELD + r)*PSZ + j0;
        int s = 0, c = 0;
        #pragma unroll
        for (int j4 = 0; j4 < 4; ++j4) {
            int4 v = *(const int4*)(rp + j4*4);
            s += v.x + v.y + v.z + v.w;
            if (v.x != PSZ) { atomicAdd(&hist[k*128 + v.x], 1); c++; }
            if (v.y != PSZ) { atomicAdd(&hist[k*128 + v.y], 1); c++; }
            if (v.z != PSZ) { atomicAdd(&hist[k*128 + v.z], 1); c++; }
            if (v.w != PSZ) { atomicAdd(&hist[k*128 + v.w], 1); c++; }
        }
        atomicAdd(&rowAcc[k], s + (c << 20));
    }
    __syncthreads();
    // gated S -> SS bf16 (swizzled [k][p])
    for (int i = t; i < 4096; i += 256) {
        int k = i >> 7, p = i & 127;
        int ra = rowAcc[k];
        float val = ((ra & 0xFFFFF) > 0) ? (float)hist[k*128 + p] : 0.f;
        SS[k*128 + (((p >> 3) ^ (k & 7))*8) + (p & 7)] = (unsigned short)f2bf(val);
    }
    // (loop's first barrier orders SS fill before AS staging overwrites hist)

    f32x4 acc[2][2] = {{{0.f,0.f,0.f,0.f},{0.f,0.f,0.f,0.f}},
                       {{0.f,0.f,0.f,0.f},{0.f,0.f,0.f,0.f}}};

    for (int ch = 0; ch < 6; ++ch) {
        __syncthreads();
        // transpose-pack rel chunk -> BS[g][h]
        #pragma unroll
        for (int i = 0; i < 4; ++i) {
            int g_l = gq2*4 + i;
            int hloc = hq*4;
            unsigned int p0 = f2bf(((const float*)&buf[0])[i]);
            unsigned int p1 = f2bf(((const float*)&buf[1])[i]);
            unsigned int p2 = f2bf(((const float*)&buf[2])[i]);
            unsigned int p3 = f2bf(((const float*)&buf[3])[i]);
            int cs = (hloc >> 3) ^ ((g_l >> 2) & 7);
            uint2 d; d.x = p0 | (p1 << 16); d.y = p2 | (p3 << 16);
            *(uint2*)&BS[g_l*128 + cs*8 + (hloc & 4)] = d;
        }
        // stage P0 chunk -> AS[p][h] (f32 -> bf16 on the fly)
        #pragma unroll
        for (int q = 0; q < 8; ++q) {
            int idx = t + q*256;
            int row = idx >> 4, c = idx & 15;
            const float* pp = &P0[(size_t)row*HID + ch*128 + c*8];
            float4 a0 = *(const float4*)pp;
            float4 a1 = *(const float4*)(pp + 4);
            uint4 d;
            d.x = f2bf(a0.x) | (f2bf(a0.y) << 16);
            d.y = f2bf(a0.z) | (f2bf(a0.w) << 16);
            d.z = f2bf(a1.x) | (f2bf(a1.y) << 16);
            d.w = f2bf(a1.z) | (f2bf(a1.w) << 16);
            *(uint4*)&AS[row*128 + (c ^ (row & 7))*8] = d;
        }
        __syncthreads();
        if (ch < 5) {
            int hn = ch*128 + 128;
            #pragma unroll
            for (int rr = 0; rr < 4; ++rr)
                buf[rr] = *(const float4*)&rel[relb + (size_t)(hn + hq*4 + rr)*HID + gq2*4];
        }
        #pragma unroll
        for (int kk = 0; kk < 4; ++kk) {
            #pragma unroll
            for (int mf = 0; mf < 2; ++mf) {
                int arow = wave*32 + mf*16 + (lane & 15);
                int cA = (kk*4 + (lane >> 4)) ^ (arow & 7);
                bf16x8 a = *(const bf16x8*)&AS[arow*128 + cA*8];
                #pragma unroll
                for (int nf = 0; nf < 2; ++nf) {
                    int brow = nf*16 + (lane & 15);
                    int cB = (kk*4 + (lane >> 4)) ^ ((brow >> 2) & 7);
                    bf16x8 b = *(const bf16x8*)&BS[brow*128 + cB*8];
                    acc[mf][nf] = __builtin_amdgcn_mfma_f32_16x16x32_bf16(a, b, acc[mf][nf], 0, 0, 0);
                }
            }
        }
    }
    __syncthreads();   // AS/BS dead; alias as YST

    // write Y tile (global [r][p][g]) + YST (LDS [g][p] swizzled)
    #pragma unroll
    for (int mf = 0; mf < 2; ++mf) {
        #pragma unroll
        for (int nf = 0; nf < 2; ++nf) {
            #pragma unroll
            for (int j = 0; j < 4; ++j) {
                int p = wave*32 + mf*16 + (lane >> 4)*4 + j;
                int g_l = nf*16 + (lane & 15);
                unsigned short yb = (unsigned short)f2bf(acc[mf][nf][j]);
                Y_bf[((size_t)r*128 + p)*HID + g0 + g_l] = yb;
                YST[g_l*128 + (((p >> 3) ^ ((g_l >> 2) & 7))*8) + (p & 7)] = yb;
            }
        }
    }
    __syncthreads();
    // prop tile: [32 k x 32 g] = S_r[32x128] x Ytile[128x32]; waves 0,1
    if (wave < 2) {
        f32x4 acc2[2] = {{0.f,0.f,0.f,0.f},{0.f,0.f,0.f,0.f}};
        #pragma unroll
        for (int kk = 0; kk < 4; ++kk) {
            int brow = wave*16 + (lane & 15);
            int cB = (kk*4 + (lane >> 4)) ^ ((brow >> 2) & 7);
            bf16x8 b = *(const bf16x8*)&YST[brow*128 + cB*8];
            #pragma unroll
            for (int mf = 0; mf < 2; ++mf) {
                int arow = mf*16 + (lane & 15);
                int cA = (kk*4 + (lane >> 4)) ^ (arow & 7);
                bf16x8 a = *(const bf16x8*)&SS[arow*128 + cA*8];
                acc2[mf] = __builtin_amdgcn_mfma_f32_16x16x32_bf16(a, b, acc2[mf], 0, 0, 0);
            }
        }
        int gg = g0 + wave*16 + (lane & 15);
        #pragma unroll
        for (int mf = 0; mf < 2; ++mf) {
            #pragma unroll
            for (int j = 0; j < 4; ++j) {
                int kkk = mf*16 + (lane >> 4)*4 + j;
                atomicAdd(&prop[(size_t)kkk*HID + gg], acc2[mf][j]);
            }
        }
    }
}

// =========================================================================
// K_B (k_tail): 24 blocks x 256 thr, self-sufficient.
//   bid < 16 : zz_r = Y_r x pt^T + CE loss (own histogram for S); float
//              done-counter; last block stores outLoss
//   bid >=16 : proto scatter-update + logits (own nAct scan)
// =========================================================================
__global__ __launch_bounds__(256) void k_tail(
        const int* __restrict__ labels, const int* __restrict__ relIds,
        const float* __restrict__ P0, const unsigned short* __restrict__ Y_bf,
        const float* __restrict__ prop, const float* __restrict__ inst,
        float* __restrict__ lossAcc, float* __restrict__ naAcc,
        float* __restrict__ totAcc, float* __restrict__ doneF,
        float* __restrict__ outProto, float* __restrict__ outLogits,
        float* __restrict__ outLoss)
{
    __shared__ __align__(16) char shraw[81920];   // ptS 48K + AS 32K | protoS 49.4K
    __shared__ int histB[4096];                   // [k][p] (zz blocks)
    __shared__ int lab[32], rankS[32], luS[32], ownS[128], rowAcc[32];
    __shared__ float redF[256];
    __shared__ int redI[256];
    __shared__ float nActS[16];
    __shared__ int kS2[16];
    const int bid = blockIdx.x, t = threadIdx.x;
    const int wave = t >> 6, lane = t & 63;

    if (t < 32) { lab[t] = labels[t]; rowAcc[t] = 0; }
    if (t < 128) ownS[t] = -1;
    __syncthreads();
    if (t < 32) { int rk = 0; for (int j = 0; j < 32; ++j) rk += (lab[j] < lab[t]); rankS[t] = rk; }
    __syncthreads();
    if (t < 32) luS[rankS[t]] = lab[t];
    __syncthreads();
    if (t < 32) ownS[luS[t]] = t;
    __syncthreads();

    if (bid < 16) {
        // ---- zz_r + CE loss ----
        const int r = bid;
        unsigned short* ptS = (unsigned short*)shraw;            // [k][g], c^=(k&7)
        unsigned short* AS  = (unsigned short*)shraw + 24576;    // [p][g-chunk], c^=(p&7)
        // stage pt from P0 f32 (gather rows lu[k])
        for (int i = t; i < 3072; i += 256) {
            int k = i / 96, c = i % 96;
            const float* pp = &P0[(size_t)luS[k]*HID + c*8];
            float4 a0 = *(const float4*)pp;
            float4 a1 = *(const float4*)(pp + 4);
            uint4 d;
            d.x = f2bf(a0.x) | (f2bf(a0.y) << 16);
            d.y = f2bf(a0.z) | (f2bf(a0.w) << 16);
            d.z = f2bf(a1.x) | (f2bf(a1.y) << 16);
            d.w = f2bf(a1.z) | (f2bf(a1.w) << 16);
            *(uint4*)&ptS[k*768 + (c ^ (k & 7))*8] = d;
        }
        // own S histogram
        for (int i = t; i < 4096; i += 256) histB[i] = 0;
        __syncthreads();
        {
            int k = t >> 3, j0 = (t & 7) * 16;
            const int* rp = relIds + ((size_t)rankS[k]*NRELD + r)*PSZ + j0;
            int s = 0, c = 0;
            #pragma unroll
            for (int j4 = 0; j4 < 4; ++j4) {
                int4 v = *(const int4*)(rp + j4*4);
                s += v.x + v.y + v.z + v.w;
                if (v.x != PSZ) { atomicAdd(&histB[k*128 + v.x], 1); c++; }
                if (v.y != PSZ) { atomicAdd(&histB[k*128 + v.y], 1); c++; }
                if (v.z != PSZ) { atomicAdd(&histB[k*128 + v.z], 1); c++; }
                if (v.w != PSZ) { atomicAdd(&histB[k*128 + v.w], 1); c++; }
            }
            atomicAdd(&rowAcc[k], s + (c << 20));
        }
        f32x4 acc[2][2] = {{{0.f,0.f,0.f,0.f},{0.f,0.f,0.f,0.f}},
                           {{0.f,0.f,0.f,0.f},{0.f,0.f,0.f,0.f}}};
        for (int ch = 0; ch < 6; ++ch) {
            __syncthreads();
            #pragma unroll
            for (int q = 0; q < 8; ++q) {
                int idx = t + q*256;
                int row = idx >> 4, c = idx & 15;
                *(uint4*)&AS[row*128 + (c ^ (row & 7))*8] =
                    *(const uint4*)&Y_bf[((size_t)r*128 + row)*HID + ch*128 + c*8];
            }
            __syncthreads();
            #pragma unroll
            for (int kk = 0; kk < 4; ++kk) {
                #pragma unroll
                for (int mf = 0; mf < 2; ++mf) {
                    int arow = wave*32 + mf*16 + (lane & 15);
                    int cA = (kk*4 + (lane >> 4)) ^ (arow & 7);
                    bf16x8 a = *(const bf16x8*)&AS[arow*128 + cA*8];
                    #pragma unroll
                    for (int nf = 0; nf < 2; ++nf) {
                        int brow = nf*16 + (lane & 15);
                        int cB = (ch*16 + kk*4 + (lane >> 4)) ^ (brow & 7);
                        bf16x8 b = *(const bf16x8*)&ptS[brow*768 + cB*8];
                        acc[mf][nf] = __builtin_amdgcn_mfma_f32_16x16x32_bf16(a, b, acc[mf][nf], 0, 0, 0);
                    }
                }
            }
        }
        float term = 0.f;
        #pragma unroll
        for (int mf = 0; mf < 2; ++mf) {
            #pragma unroll
            for (int nf = 0; nf < 2; ++nf) {
                #pragma unroll
                for (int j = 0; j < 4; ++j) {
                    int p = wave*32 + mf*16 + (lane >> 4)*4 + j;
                    int kkk = nf*16 + (lane & 15);
                    int ra = rowAcc[kkk];
                    if ((ra & 0xFFFFF) > 0) {
                        int Si = histB[kkk*128 + p];
                        if (Si != 0) {
                            float z = acc[mf][nf][j];
                            float s = 1.f / (1.f + expf(-z));
                            term += (float)Si * (logf(expf(1.f - s) + expf(s)) - s);
                        }
                    }
                }
            }
        }
        redF[t] = term;
        __syncthreads();
        for (int off = 128; off; off >>= 1) {
            if (t < off) redF[t] += redF[t + off];
            __syncthreads();
        }
        if (t == 0) atomicAdd(lossAcc, redF[0]);
        __syncthreads();
        // na_r and any-active from rowAcc
        float nv = 0.f; int anyv = 0;
        if (t < 32) {
            int ra = rowAcc[t];
            if ((ra & 0xFFFFF) > 0) { nv = (float)(ra >> 20); anyv = 1; }
        }
        redF[t] = nv; redI[t] = anyv;
        __syncthreads();
        for (int off = 128; off; off >>= 1) {
            if (t < off) { redF[t] += redF[t + off]; redI[t] |= redI[t + off]; }
            __syncthreads();
        }
        if (t == 0) {
            atomicAdd(naAcc, redF[0]);
            atomicAdd(totAcc, (float)redI[0]);
            __threadfence();
            float old = atomicAdd(doneF, 1.0f);
            if (old > 14.5f) {                    // 16th (last) zz block
                __threadfence();
                float la = atomicAdd(lossAcc, 0.f);
                float na = atomicAdd(naAcc, 0.f);
                float tt = atomicAdd(totAcc, 0.f);
                outLoss[0] = (tt > 0.5f)
                    ? (la + (65536.f - na) * 0.6931471805599453f) * (1.f/65536.f)
                    : 0.f;
            }
        }
    } else {
        // ---- proto update + logits, 16 p-rows per block ----
        float* protoS = (float*)shraw;       // [16][772] padded
        const int PSTR = 772;
        int pb = (bid - 16) * 16;
        if (t < 16) { kS2[t] = ownS[pb + t]; nActS[t] = 0.f; }
        __syncthreads();
        {   // nAct scan: thread (pl = t>>4, row i = t&15)
            int pl = t >> 4, i = t & 15;
            int k = kS2[pl];
            float contrib = 0.f;
            if (k >= 0) {
                const int* rp = relIds + ((size_t)rankS[k]*NRELD + i)*PSZ;
                int s = 0, c = 0;
                #pragma unroll 8
                for (int j = 0; j < 128; j += 4) {
                    int4 v = *(const int4*)(rp + j);
                    s += v.x + v.y + v.z + v.w;
                    c += (v.x != PSZ) + (v.y != PSZ) + (v.z != PSZ) + (v.w != PSZ);
                }
                if (s > 0) contrib = (float)c;
            }
            if (contrib != 0.f) atomicAdd(&nActS[pl], contrib);
        }
        __syncthreads();
        for (int it = t; it < 16*192; it += 256) {
            int pl = it / 192, c = it % 192;
            int p = pb + pl;
            float4 old = *(const float4*)&P0[(size_t)p*HID + c*4];
            float4 o = old;
            int k = kS2[pl]; float n = nActS[pl];
            if (k >= 0 && n > 0.f) {
                float4 pr = *(const float4*)&prop[(size_t)k*HID + c*4];
                float invn = 0.5f / n;
                o.x = 0.5f*old.x + pr.x*invn;
                o.y = 0.5f*old.y + pr.y*invn;
                o.z = 0.5f*old.z + pr.z*invn;
                o.w = 0.5f*old.w + pr.w*invn;
            }
            *(float4*)&outProto[(size_t)p*HID + c*4] = o;
            protoS[pl*PSTR + c*4+0] = o.x;
            protoS[pl*PSTR + c*4+1] = o.y;
            protoS[pl*PSTR + c*4+2] = o.z;
            protoS[pl*PSTR + c*4+3] = o.w;
        }
        __syncthreads();
        int b = t & 31, p2 = (t >> 5) * 2;
        const float4* ir = (const float4*)&inst[(size_t)b*HID];
        float a0 = 0.f, a1 = 0.f;
        for (int q = 0; q < HID/4; ++q) {
            float4 iv = ir[q];
            float4 pv0 = *(const float4*)&protoS[p2*PSTR + q*4];
            float4 pv1 = *(const float4*)&protoS[(p2+1)*PSTR + q*4];
            float dx = iv.x - pv0.x, dy = iv.y - pv0.y, dz = iv.z - pv0.z, dw = iv.w - pv0.w;
            a0 += dx*dx + dy*dy + dz*dz + dw*dw;
            dx = iv.x - pv1.x; dy = iv.y - pv1.y; dz = iv.z - pv1.z; dw = iv.w - pv1.w;
            a1 += dx*dx + dy*dy + dz*dz + dw*dw;
        }
        outLogits[b*PSZ + pb + p2]     = -a0;
        outLogits[b*PSZ + pb + p2 + 1] = -a1;
    }
}

// -------------------------------------------------------------------------
extern "C" void kernel_launch(void* const* d_in, const int* in_sizes, int n_in,
                              void* d_out, int out_size, void* d_ws, size_t ws_size,
                              hipStream_t stream)
{
    const float* inst  = (const float*)d_in[0];   // [32,768]
    const float* rel   = (const float*)d_in[1];   // [16,768,768]
    const int* relIds  = (const int*)d_in[2];     // [32,16,128]
    const int* labels  = (const int*)d_in[3];     // [32]
    const float* P0    = (const float*)d_in[4];   // [128,768]
    float* out = (float*)d_out;
    float* outLogits = out;            // 4096
    float* outLoss   = out + 4096;     // 1
    float* outProto  = out + 4097;     // 98304

    char* ws = (char*)d_ws;
    unsigned short* Y_bf = (unsigned short*)(ws + 0);   // 3145728 B
    float* prop    = (float*)(ws + 3145728);            // 98304 B
    float* lossAcc = (float*)(ws + 3244032);            // poison ~ -1.4e-13: OK
    float* naAcc   = (float*)(ws + 3244160);
    float* totAcc  = (float*)(ws + 3244288);
    float* doneF   = (float*)(ws + 3244416);

    k_Y<<<384, 256, 0, stream>>>(labels, relIds, rel, P0, Y_bf, prop);
    k_tail<<<24, 256, 0, stream>>>(labels, relIds, P0, Y_bf, prop, inst,
                                   lossAcc, naAcc, totAcc, doneF,
                                   outProto, outLogits, outLoss);
}

// Round 9
// 129.855 us; speedup vs baseline: 1.0961x; 1.0961x over previous
//
#include <hip/hip_runtime.h>
#include <hip/hip_bf16.h>
#include <math.h>

#define K_B 32
#define NRELD 16
#define PSZ 128
#define HID 768

using bf16x8 = __attribute__((ext_vector_type(8))) short;
using f32x4  = __attribute__((ext_vector_type(4))) float;

__device__ __forceinline__ unsigned int f2bf(float x) {   // fp32 -> bf16 bits (RNE)
    unsigned int u = __float_as_uint(x);
    return (u + 0x7fffu + ((u >> 16) & 1u)) >> 16;
}
__device__ __forceinline__ float bf2f(unsigned short b) {
    return __uint_as_float(((unsigned int)b) << 16);
}

// -------------------------------------------------------------------------
// K1 (k_prep): per-(k,r) gated histogram S + rowflag/cntRow; blocks<128
// convert P0 (P0_bf, pt_bf); blocks<96 zero prop; block 0 zeroes loss/done.
// grid 512 (k*16+r), 192 thr
// -------------------------------------------------------------------------
__global__ __launch_bounds__(192) void k_prep(
        const int* __restrict__ labels, const int* __restrict__ relIds,
        const float* __restrict__ P0,
        unsigned short* __restrict__ S_bf, unsigned short* __restrict__ P0_bf,
        unsigned short* __restrict__ pt_bf,
        int* __restrict__ rowflag, int* __restrict__ cntRow,
        float* __restrict__ prop, float* __restrict__ lossAcc,
        int* __restrict__ done)
{
    int bid = blockIdx.x, t = threadIdx.x;
    int k = bid >> 4, r = bid & 15;
    __shared__ int lab[32], rankS[32], luS[32], ownS[128];
    __shared__ int hist[128], redS[128];
    if (t < 32) lab[t] = labels[t];
    if (t < 128) { hist[t] = 0; ownS[t] = -1; }
    __syncthreads();
    if (t < 32) { int rk = 0; for (int j = 0; j < 32; ++j) rk += (lab[j] < lab[t]); rankS[t] = rk; }
    __syncthreads();
    if (t < 32) luS[rankS[t]] = lab[t];
    __syncthreads();
    if (t < 32) ownS[luS[t]] = t;
    __syncthreads();

    if (t < 128) {
        int id = relIds[((size_t)rankS[k]*NRELD + r)*PSZ + t];
        int isv = (id != PSZ);
        if (isv) atomicAdd(&hist[id], 1);
        redS[t] = id + (isv << 20);          // rowsum (<2^20) | cnt<<20
    }
    __syncthreads();
    for (int off = 64; off; off >>= 1) {
        if (t < off) redS[t] += redS[t + off];
        __syncthreads();
    }
    int rowsum = redS[0] & 0xFFFFF;
    int cnt    = redS[0] >> 20;
    int rf     = (rowsum > 0);
    if (t < 128)
        S_bf[(size_t)bid*128 + t] = (unsigned short)f2bf(rf ? (float)hist[t] : 0.f);
    if (t == 0) { rowflag[bid] = rf; cntRow[bid] = cnt; }
    if (bid == 0 && t == 0) { lossAcc[0] = 0.f; done[0] = 0; }
    if (bid < 96 && t < 64) {                 // zero prop (32x768 f32)
        float4 z = {0.f, 0.f, 0.f, 0.f};
        ((float4*)prop)[bid*64 + t] = z;
    }
    if (bid < 128) {                          // P0 conversions (row p = bid)
        int p = bid;
        float4 v4 = *(const float4*)&P0[(size_t)p*HID + t*4];
        unsigned int b0 = f2bf(v4.x), b1 = f2bf(v4.y), b2 = f2bf(v4.z), b3 = f2bf(v4.w);
        uint2 d; d.x = b0 | (b1 << 16); d.y = b2 | (b3 << 16);
        *(uint2*)&P0_bf[(size_t)p*HID + t*4] = d;
        int kk = ownS[p];
        if (kk >= 0) *(uint2*)&pt_bf[(size_t)kk*HID + t*4] = d;
    }
}

// -------------------------------------------------------------------------
// K2 (k_Y): Y_r = P0 x Rel_r  (contraction h, rel transposed in LDS)
//   + fused prop-tile: prop[k, g-slab] += S_r x Ytile
// grid 384 (r = bid&15, gs = bid>>4: 24 g-slabs of 32), 256 thr, 40 KB LDS
// -------------------------------------------------------------------------
__global__ __launch_bounds__(256) void k_Y(
        const float* __restrict__ rel, const unsigned short* __restrict__ P0_bf,
        const unsigned short* __restrict__ S_bf,
        unsigned short* __restrict__ Y_bf, float* __restrict__ prop)
{
    __shared__ unsigned short sh[16384 + 4096];   // AS 128x128 | BS 32x128
    unsigned short* AS  = sh;                     // [p][h-chunk], c^=(p&7)
    unsigned short* BS  = sh + 16384;             // [g][h-chunk], c^=((g>>2)&7)
    unsigned short* YST = sh;                     // phase2: [g][p], aliases AS
    unsigned short* SS  = sh + 4096;              // phase2: [k][p], aliases AS

    const int bid = blockIdx.x, t = threadIdx.x;
    const int wave = t >> 6, lane = t & 63;
    const int r = bid & 15, gs = bid >> 4;
    const int g0 = gs * 32;

    const int gq2 = t & 7;                   // float4-in-g (g_l = gq2*4)
    const int hq  = t >> 3;                  // 0..31  (h rows hq*4 .. +3)
    const size_t relb = (size_t)r*HID*HID + g0;

    float4 buf[4];
    #pragma unroll
    for (int rr = 0; rr < 4; ++rr)
        buf[rr] = *(const float4*)&rel[relb + (size_t)(hq*4 + rr)*HID + gq2*4];

    f32x4 acc[2][2] = {{{0.f,0.f,0.f,0.f},{0.f,0.f,0.f,0.f}},
                       {{0.f,0.f,0.f,0.f},{0.f,0.f,0.f,0.f}}};

    for (int ch = 0; ch < 6; ++ch) {
        __syncthreads();
        // transpose-pack rel chunk -> BS[g][h]
        #pragma unroll
        for (int i = 0; i < 4; ++i) {
            int g_l = gq2*4 + i;
            int hloc = hq*4;
            unsigned int p0 = f2bf(((const float*)&buf[0])[i]);
            unsigned int p1 = f2bf(((const float*)&buf[1])[i]);
            unsigned int p2 = f2bf(((const float*)&buf[2])[i]);
            unsigned int p3 = f2bf(((const float*)&buf[3])[i]);
            int cs = (hloc >> 3) ^ ((g_l >> 2) & 7);
            uint2 d; d.x = p0 | (p1 << 16); d.y = p2 | (p3 << 16);
            *(uint2*)&BS[g_l*128 + cs*8 + (hloc & 4)] = d;
        }
        // stage P0 chunk -> AS[p][h]
        #pragma unroll
        for (int q = 0; q < 8; ++q) {
            int idx = t + q*256;
            int row = idx >> 4, c = idx & 15;
            *(uint4*)&AS[row*128 + (c ^ (row & 7))*8] =
                *(const uint4*)&P0_bf[(size_t)row*HID + ch*128 + c*8];
        }
        __syncthreads();
        if (ch < 5) {
            int hn = ch*128 + 128;
            #pragma unroll
            for (int rr = 0; rr < 4; ++rr)
                buf[rr] = *(const float4*)&rel[relb + (size_t)(hn + hq*4 + rr)*HID + gq2*4];
        }
        #pragma unroll
        for (int kk = 0; kk < 4; ++kk) {
            #pragma unroll
            for (int mf = 0; mf < 2; ++mf) {
                int arow = wave*32 + mf*16 + (lane & 15);
                int cA = (kk*4 + (lane >> 4)) ^ (arow & 7);
                bf16x8 a = *(const bf16x8*)&AS[arow*128 + cA*8];
                #pragma unroll
                for (int nf = 0; nf < 2; ++nf) {
                    int brow = nf*16 + (lane & 15);
                    int cB = (kk*4 + (lane >> 4)) ^ ((brow >> 2) & 7);
                    bf16x8 b = *(const bf16x8*)&BS[brow*128 + cB*8];
                    acc[mf][nf] = __builtin_amdgcn_mfma_f32_16x16x32_bf16(a, b, acc[mf][nf], 0, 0, 0);
                }
            }
        }
    }
    __syncthreads();   // AS/BS dead; alias as YST/SS

    // write Y tile (global, [r][p][g]) + YST (LDS, [g][p] swizzled)
    #pragma unroll
    for (int mf = 0; mf < 2; ++mf) {
        #pragma unroll
        for (int nf = 0; nf < 2; ++nf) {
            #pragma unroll
            for (int j = 0; j < 4; ++j) {
                int p = wave*32 + mf*16 + (lane >> 4)*4 + j;
                int g_l = nf*16 + (lane & 15);
                unsigned short yb = (unsigned short)f2bf(acc[mf][nf][j]);
                Y_bf[((size_t)r*128 + p)*HID + g0 + g_l] = yb;
                YST[g_l*128 + (((p >> 3) ^ ((g_l >> 2) & 7))*8) + (p & 7)] = yb;
            }
        }
    }
    // stage S_r -> SS[k][p]
    #pragma unroll
    for (int q = 0; q < 2; ++q) {
        int idx = t + q*256;
        int row = idx >> 4, c = idx & 15;
        *(uint4*)&SS[row*128 + (c ^ (row & 7))*8] =
            *(const uint4*)&S_bf[((size_t)row*NRELD + r)*128 + c*8];
    }
    __syncthreads();
    // prop tile: [32 k x 32 g] = S_r[32x128] x Ytile[128x32g]; waves 0,1
    if (wave < 2) {
        f32x4 acc2[2] = {{0.f,0.f,0.f,0.f},{0.f,0.f,0.f,0.f}};
        #pragma unroll
        for (int kk = 0; kk < 4; ++kk) {
            int brow = wave*16 + (lane & 15);
            int cB = (kk*4 + (lane >> 4)) ^ ((brow >> 2) & 7);
            bf16x8 b = *(const bf16x8*)&YST[brow*128 + cB*8];
            #pragma unroll
            for (int mf = 0; mf < 2; ++mf) {
                int arow = mf*16 + (lane & 15);
                int cA = (kk*4 + (lane >> 4)) ^ (arow & 7);
                bf16x8 a = *(const bf16x8*)&SS[arow*128 + cA*8];
                acc2[mf] = __builtin_amdgcn_mfma_f32_16x16x32_bf16(a, b, acc2[mf], 0, 0, 0);
            }
        }
        int gg = g0 + wave*16 + (lane & 15);
        #pragma unroll
        for (int mf = 0; mf < 2; ++mf) {
            #pragma unroll
            for (int j = 0; j < 4; ++j) {
                int kkk = mf*16 + (lane >> 4)*4 + j;
                atomicAdd(&prop[(size_t)kkk*HID + gg], acc2[mf][j]);
            }
        }
    }
}

// -------------------------------------------------------------------------
// K3 (k_tail): 24 blocks x 256 thr
//   bid < 16 : zz_r = Y_r x pt^T (K=768 over g) + CE loss; done-counter
//              finalize of outLoss by last zz block
//   bid >=16 : proto scatter-update + logits (16 p-rows / block)
// -------------------------------------------------------------------------
__global__ __launch_bounds__(256) void k_tail(
        const unsigned short* __restrict__ Y_bf, const unsigned short* __restrict__ pt_bf,
        const unsigned short* __restrict__ S_bf, float* __restrict__ lossAcc,
        int* __restrict__ done,
        const float* __restrict__ P0, const float* __restrict__ prop,
        const int* __restrict__ rowflag, const int* __restrict__ cntRow,
        const int* __restrict__ labels, const float* __restrict__ inst,
        float* __restrict__ outProto, float* __restrict__ outLogits,
        float* __restrict__ outLoss)
{
    __shared__ __align__(16) char shraw[81920];   // ptS 48K + AS 32K | protoS 49.4K
    __shared__ int lab[32], rankS[32], luS[32], ownS[128];
    __shared__ float redF[256];
    __shared__ int redI[256];
    __shared__ float nActS[16];
    __shared__ int kS2[16];
    const int bid = blockIdx.x, t = threadIdx.x;
    const int wave = t >> 6, lane = t & 63;

    if (t < 32) lab[t] = labels[t];
    if (t < 128) ownS[t] = -1;
    __syncthreads();
    if (t < 32) { int rk = 0; for (int j = 0; j < 32; ++j) rk += (lab[j] < lab[t]); rankS[t] = rk; }
    __syncthreads();
    if (t < 32) luS[rankS[t]] = lab[t];
    __syncthreads();
    if (t < 32) ownS[luS[t]] = t;
    __syncthreads();

    if (bid < 16) {
        // ---- zz_r + CE loss ----
        const int r = bid;
        unsigned short* ptS = (unsigned short*)shraw;            // [k][g], c^=(k&7)
        unsigned short* AS  = (unsigned short*)shraw + 24576;    // [p][g-chunk], c^=(p&7)
        for (int i = t; i < 3072; i += 256) {
            int k = i / 96, c = i % 96;
            uint4 d = *(const uint4*)&pt_bf[(size_t)k*HID + c*8];
            *(uint4*)&ptS[k*768 + (c ^ (k & 7))*8] = d;
        }
        f32x4 acc[2][2] = {{{0.f,0.f,0.f,0.f},{0.f,0.f,0.f,0.f}},
                           {{0.f,0.f,0.f,0.f},{0.f,0.f,0.f,0.f}}};
        for (int ch = 0; ch < 6; ++ch) {
            __syncthreads();
            #pragma unroll
            for (int q = 0; q < 8; ++q) {
                int idx = t + q*256;
                int row = idx >> 4, c = idx & 15;
                *(uint4*)&AS[row*128 + (c ^ (row & 7))*8] =
                    *(const uint4*)&Y_bf[((size_t)r*128 + row)*HID + ch*128 + c*8];
            }
            __syncthreads();
            #pragma unroll
            for (int kk = 0; kk < 4; ++kk) {
                #pragma unroll
                for (int mf = 0; mf < 2; ++mf) {
                    int arow = wave*32 + mf*16 + (lane & 15);
                    int cA = (kk*4 + (lane >> 4)) ^ (arow & 7);
                    bf16x8 a = *(const bf16x8*)&AS[arow*128 + cA*8];
                    #pragma unroll
                    for (int nf = 0; nf < 2; ++nf) {
                        int brow = nf*16 + (lane & 15);
                        int cB = (ch*16 + kk*4 + (lane >> 4)) ^ (brow & 7);
                        bf16x8 b = *(const bf16x8*)&ptS[brow*768 + cB*8];
                        acc[mf][nf] = __builtin_amdgcn_mfma_f32_16x16x32_bf16(a, b, acc[mf][nf], 0, 0, 0);
                    }
                }
            }
        }
        float term = 0.f;
        #pragma unroll
        for (int mf = 0; mf < 2; ++mf) {
            #pragma unroll
            for (int nf = 0; nf < 2; ++nf) {
                #pragma unroll
                for (int j = 0; j < 4; ++j) {
                    int p = wave*32 + mf*16 + (lane >> 4)*4 + j;
                    int kkk = nf*16 + (lane & 15);
                    float S = bf2f(S_bf[((size_t)kkk*NRELD + r)*128 + p]);
                    if (S != 0.f) {
                        float z = acc[mf][nf][j];
                        float s = 1.f / (1.f + expf(-z));
                        term += S * (logf(expf(1.f - s) + expf(s)) - s);
                    }
                }
            }
        }
        redF[t] = term;
        __syncthreads();
        for (int off = 128; off; off >>= 1) {
            if (t < off) redF[t] += redF[t + off];
            __syncthreads();
        }
        if (t == 0) atomicAdd(lossAcc, redF[0]);
        __threadfence();
        __syncthreads();
        float s2 = 0.f; int tot = 0;
        #pragma unroll
        for (int q = 0; q < 2; ++q) {
            int rr2 = t + 256*q;
            int rf = rowflag[rr2];
            tot |= rf;
            if (rf) s2 += (float)cntRow[rr2];
        }
        redF[t] = s2; redI[t] = tot;
        __syncthreads();
        for (int off = 128; off; off >>= 1) {
            if (t < off) { redF[t] += redF[t + off]; redI[t] |= redI[t + off]; }
            __syncthreads();
        }
        if (t == 0) {
            int old = atomicAdd(done, 1);
            if (old == 15) {
                __threadfence();
                float cur = atomicAdd(lossAcc, 0.f);   // atomic read of final sum
                outLoss[0] = redI[0]
                    ? (cur + (65536.f - redF[0]) * 0.6931471805599453f) * (1.f/65536.f)
                    : 0.f;
            }
        }
    } else {
        // ---- proto update + logits, 16 p-rows per block ----
        float* protoS = (float*)shraw;       // [16][772] padded
        const int PSTR = 772;
        int pb = (bid - 16) * 16;
        if (t < 16) {
            int p = pb + t;
            int k = ownS[p];
            float n = 0.f;
            if (k >= 0)
                for (int i = 0; i < 16; ++i) {
                    int rr2 = k*NRELD + i;
                    if (rowflag[rr2]) n += (float)cntRow[rr2];
                }
            nActS[t] = n; kS2[t] = k;
        }
        __syncthreads();
        for (int it = t; it < 16*192; it += 256) {
            int pl = it / 192, c = it % 192;
            int p = pb + pl;
            float4 old = *(const float4*)&P0[(size_t)p*HID + c*4];
            float4 o = old;
            int k = kS2[pl]; float n = nActS[pl];
            if (k >= 0 && n > 0.f) {
                float4 pr = *(const float4*)&prop[(size_t)k*HID + c*4];
                float invn = 0.5f / n;
                o.x = 0.5f*old.x + pr.x*invn;
                o.y = 0.5f*old.y + pr.y*invn;
                o.z = 0.5f*old.z + pr.z*invn;
                o.w = 0.5f*old.w + pr.w*invn;
            }
            *(float4*)&outProto[(size_t)p*HID + c*4] = o;
            protoS[pl*PSTR + c*4+0] = o.x;
            protoS[pl*PSTR + c*4+1] = o.y;
            protoS[pl*PSTR + c*4+2] = o.z;
            protoS[pl*PSTR + c*4+3] = o.w;
        }
        __syncthreads();
        int b = t & 31, p2 = (t >> 5) * 2;
        const float4* ir = (const float4*)&inst[(size_t)b*HID];
        float a0 = 0.f, a1 = 0.f;
        for (int q = 0; q < HID/4; ++q) {
            float4 iv = ir[q];
            float4 pv0 = *(const float4*)&protoS[p2*PSTR + q*4];
            float4 pv1 = *(const float4*)&protoS[(p2+1)*PSTR + q*4];
            float dx = iv.x - pv0.x, dy = iv.y - pv0.y, dz = iv.z - pv0.z, dw = iv.w - pv0.w;
            a0 += dx*dx + dy*dy + dz*dz + dw*dw;
            dx = iv.x - pv1.x; dy = iv.y - pv1.y; dz = iv.z - pv1.z; dw = iv.w - pv1.w;
            a1 += dx*dx + dy*dy + dz*dz + dw*dw;
        }
        outLogits[b*PSZ + pb + p2]     = -a0;
        outLogits[b*PSZ + pb + p2 + 1] = -a1;
    }
}

// -------------------------------------------------------------------------
extern "C" void kernel_launch(void* const* d_in, const int* in_sizes, int n_in,
                              void* d_out, int out_size, void* d_ws, size_t ws_size,
                              hipStream_t stream)
{
    const float* inst  = (const float*)d_in[0];   // [32,768]
    const float* rel   = (const float*)d_in[1];   // [16,768,768]
    const int* relIds  = (const int*)d_in[2];     // [32,16,128]
    const int* labels  = (const int*)d_in[3];     // [32]
    const float* P0    = (const float*)d_in[4];   // [128,768]
    float* out = (float*)d_out;
    float* outLogits = out;            // 4096
    float* outLoss   = out + 4096;     // 1
    float* outProto  = out + 4097;     // 98304

    char* ws = (char*)d_ws;
    unsigned short* Y_bf    = (unsigned short*)(ws + 0);        // 3145728 B
    unsigned short* S_bf    = (unsigned short*)(ws + 3145728);  // 131072 B
    unsigned short* P0_bf   = (unsigned short*)(ws + 3276800);  // 196608 B
    unsigned short* pt_bf   = (unsigned short*)(ws + 3473408);  // 49152 B
    float* prop    = (float*)(ws + 3522560);                    // 98304 B
    float* lossAcc = (float*)(ws + 3620864);                    // 128 B
    int*   done    = (int*)(ws + 3620992);                      // 128 B
    int*   rowflag = (int*)(ws + 3621120);                      // 2048 B
    int*   cntRow  = (int*)(ws + 3623168);                      // 2048 B

    k_prep<<<512, 192, 0, stream>>>(labels, relIds, P0, S_bf, P0_bf, pt_bf,
                                    rowflag, cntRow, prop, lossAcc, done);
    k_Y<<<384, 256, 0, stream>>>(rel, P0_bf, S_bf, Y_bf, prop);
    k_tail<<<24, 256, 0, stream>>>(Y_bf, pt_bf, S_bf, lossAcc, done, P0, prop,
                                   rowflag, cntRow, labels, inst,
                                   outProto, outLogits, outLoss);
}